// Round 6
// baseline (1592.592 us; speedup 1.0000x reference)
//
#include <hip/hip_runtime.h>
#include <hip/hip_bf16.h>
#include <stdint.h>

// ---------------------------------------------------------------------------
// Alignment_49735721287759: CLIP-style alignment head on MI355X (gfx950)
// Round 6 GEMM: m201-style 256x256 8-phase schedule. BK=64, 512 thr = 8 waves
// (2Mx4N), 128KB LDS double-buffer, per-phase {ds_read || 2 stage-gloads ->
// barrier -> lgkmcnt(0) -> setprio MFMA -> barrier}, vmcnt(6) once per K-tile
// (drain only at tail), XOR-swizzled LDS reads + inverse-swizzled global src,
// bijective XCD swizzle.
// ---------------------------------------------------------------------------

typedef __attribute__((ext_vector_type(8))) short short8;
typedef __attribute__((ext_vector_type(4))) float f32x4;

__device__ __forceinline__ float bf2f(short u) {
    return __uint_as_float(((uint32_t)(uint16_t)u) << 16);
}
__device__ __forceinline__ unsigned short f2bf(float f) {
    __hip_bfloat16 h = __float2bfloat16(f);
    return *reinterpret_cast<unsigned short*>(&h);
}
__device__ __forceinline__ void gload16(const void* g, void* l) {
    __builtin_amdgcn_global_load_lds(
        (const __attribute__((address_space(1))) unsigned int*)g,
        (__attribute__((address_space(3))) unsigned int*)l, 16, 0, 0);
}
#define MFMA_(A_, B_, C_) __builtin_amdgcn_mfma_f32_16x16x32_bf16(A_, B_, C_, 0, 0, 0)

// ---------------- f32 -> bf16 convert (weights) ----------------
__global__ __launch_bounds__(256) void k_f2b(const float* __restrict__ in,
                                             unsigned short* __restrict__ out, int n) {
    for (int i = blockIdx.x * 256 + threadIdx.x; i < n; i += gridDim.x * 256)
        out[i] = f2bf(in[i]);
}

// ---------------- row L2 normalize (512-wide rows) ----------------
__global__ __launch_bounds__(256) void k_l2norm(const float* __restrict__ in,
                                                float* __restrict__ out) {
    size_t row = blockIdx.x;
    const float* x = in + row * 512;
    int t = threadIdx.x;
    float a0 = x[t], a1 = x[t + 256];
    float ss = a0 * a0 + a1 * a1;
#pragma unroll
    for (int off = 32; off; off >>= 1) ss += __shfl_xor(ss, off);
    __shared__ float s4[4];
    if ((t & 63) == 0) s4[t >> 6] = ss;
    __syncthreads();
    float tot = s4[0] + s4[1] + s4[2] + s4[3];
    float inv = 1.0f / sqrtf(tot);
    out[row * 512 + t] = a0 * inv;
    out[row * 512 + t + 256] = a1 * inv;
}

// ---------------- column sum over tokens (optionally masked) ----------------
__global__ __launch_bounds__(512) void k_colsum(const float* __restrict__ tok,
                                                const int* __restrict__ mask,
                                                float* __restrict__ out, int R) {
    int b = blockIdx.x;
    int d = threadIdx.x;  // 512 threads
    float acc = 0.f;
    for (int r = 0; r < R; r++) {
        float m = mask ? (float)mask[b * R + r] : 1.f;
        acc += m * tok[((size_t)b * R + r) * 512 + d];
    }
    out[b * 512 + d] = acc;
}

// ---------------- factored scores ----------------
__global__ __launch_bounds__(256) void k_scores(const float* __restrict__ tok,
                                                const float* __restrict__ vec,
                                                float* __restrict__ out, int R, int swap) {
    int bid = blockIdx.x;
    int i = bid >> 5, j = bid & 31;
    int tb = swap ? j : i;
    int vb = swap ? i : j;
    __shared__ float sv[512];
    for (int t = threadIdx.x; t < 512; t += 256) sv[t] = vec[vb * 512 + t];
    __syncthreads();
    int wv = threadIdx.x >> 6, lane = threadIdx.x & 63;
    for (int r = wv; r < R; r += 4) {
        const float* tr = tok + ((size_t)tb * R + r) * 512;
        float acc = 0.f;
#pragma unroll
        for (int c = 0; c < 8; c++) {
            int d = lane + c * 64;
            acc += tr[d] * sv[d];
        }
#pragma unroll
        for (int off = 32; off; off >>= 1) acc += __shfl_xor(acc, off);
        if (lane == 0) out[(size_t)bid * R + r] = acc;
    }
}

// ---------------- top-16 (values desc, ties -> lowest idx), output sorted asc
__global__ __launch_bounds__(64) void k_topk(const float* __restrict__ simg,
                                             const float* __restrict__ stxt,
                                             int* __restrict__ idx_i, int* __restrict__ idx_t) {
    int bid = blockIdx.x;  // 0..2047: first 1024 img (n=196), then txt (n=77)
    bool isimg = bid < 1024;
    int ij = isimg ? bid : bid - 1024;
    const float* s = isimg ? simg + (size_t)ij * 196 : stxt + (size_t)ij * 77;
    int n = isimg ? 196 : 77;
    int* out = (isimg ? idx_i : idx_t) + ij * 16;
    int lane = threadIdx.x;
    float v[4];
    int ids[4];
#pragma unroll
    for (int k = 0; k < 4; k++) {
        int id = lane + k * 64;
        ids[k] = id;
        v[k] = (id < n) ? s[id] : -3.0e38f;
    }
    __shared__ int sel[16];
    for (int r = 0; r < 16; r++) {
        float bv = v[0];
        int bi = ids[0];
#pragma unroll
        for (int k = 1; k < 4; k++)
            if (v[k] > bv) { bv = v[k]; bi = ids[k]; }
#pragma unroll
        for (int off = 32; off; off >>= 1) {
            float ov = __shfl_xor(bv, off);
            int oi = __shfl_xor(bi, off);
            if (ov > bv || (ov == bv && oi < bi)) { bv = ov; bi = oi; }
        }
        if (lane == 0) sel[r] = bi;
#pragma unroll
        for (int k = 0; k < 4; k++)
            if (ids[k] == bi) v[k] = -3.0e38f;
    }
    if (lane == 0) {
        for (int a = 1; a < 16; a++) {
            int key = sel[a];
            int b = a - 1;
            while (b >= 0 && sel[b] > key) { sel[b + 1] = sel[b]; b--; }
            sel[b + 1] = key;
        }
        for (int a = 0; a < 16; a++) out[a] = sel[a];
    }
}

// ---------------- gather q (f32, into d_out) / k (bf16) token rows ----------
__global__ __launch_bounds__(128) void k_gather(const float* __restrict__ img_n,
                                                const float* __restrict__ txt_n,
                                                const float* __restrict__ img_feat,
                                                const float* __restrict__ txt_feat,
                                                const float* __restrict__ img_cls,
                                                const float* __restrict__ txt_cls,
                                                const int* __restrict__ idx_i,
                                                const int* __restrict__ idx_t,
                                                float* __restrict__ q,
                                                unsigned short* __restrict__ k) {
    int rid = blockIdx.x;  // 0..69631
    int buf = rid / 34816;
    int rem = rid % 34816;
    int seq = rem / 17, t = rem % 17;
    int c = seq >> 10, ij = seq & 1023, i = ij >> 5, j = ij & 31;
    const float* src;
    if (buf == 0) {  // q tensor
        if (c == 0)
            src = (t == 0) ? img_cls : img_n + ((size_t)i * 196 + idx_i[ij * 16 + t - 1]) * 512;
        else
            src = (t == 0) ? txt_cls : txt_n + ((size_t)j * 77 + idx_t[ij * 16 + t - 1]) * 512;
    } else {  // k tensor
        if (c == 0)
            src = (t == 0) ? (txt_feat + (size_t)j * 512)
                           : txt_n + ((size_t)j * 77 + idx_t[ij * 16 + t - 1]) * 512;
        else
            src = (t == 0) ? (img_feat + (size_t)i * 512)
                           : img_n + ((size_t)i * 196 + idx_i[ij * 16 + t - 1]) * 512;
    }
    float4 v = ((const float4*)src)[threadIdx.x];
    size_t row = (size_t)seq * 17 + t;
    if (buf == 0) {
        ((float4*)(q + row * 512))[threadIdx.x] = v;
    } else {
        ushort4 o;
        o.x = f2bf(v.x); o.y = f2bf(v.y); o.z = f2bf(v.z); o.w = f2bf(v.w);
        ((ushort4*)(k + row * 512))[threadIdx.x] = o;
    }
}

// ---------------- LayerNorm 512-wide -> bf16 out; BF: input bf16 else f32 ----
template <int BF>
__global__ __launch_bounds__(256) void k_ln(const void* __restrict__ xv,
                                            const float* __restrict__ w,
                                            const float* __restrict__ b,
                                            unsigned short* __restrict__ out) {
    size_t row = blockIdx.x;
    int t = threadIdx.x;
    float a0, a1;
    if (BF) {
        const short* xr = (const short*)xv + row * 512;
        a0 = bf2f(xr[t]);
        a1 = bf2f(xr[t + 256]);
    } else {
        const float* xr = (const float*)xv + row * 512;
        a0 = xr[t];
        a1 = xr[t + 256];
    }
    float s = a0 + a1, qq = a0 * a0 + a1 * a1;
#pragma unroll
    for (int off = 32; off; off >>= 1) {
        s += __shfl_xor(s, off);
        qq += __shfl_xor(qq, off);
    }
    __shared__ float s4[4], q4[4];
    if ((t & 63) == 0) { s4[t >> 6] = s; q4[t >> 6] = qq; }
    __syncthreads();
    s = s4[0] + s4[1] + s4[2] + s4[3];
    qq = q4[0] + q4[1] + q4[2] + q4[3];
    float mean = s * (1.f / 512.f);
    float var = qq * (1.f / 512.f) - mean * mean;
    float rs = rsqrtf(var + 1e-5f);
    out[row * 512 + t] = f2bf((a0 - mean) * rs * w[t] + b[t]);
    out[row * 512 + t + 256] = f2bf((a1 - mean) * rs * w[t + 256] + b[t + 256]);
}

// ---------------- 256x256 8-phase bf16 MFMA GEMM (m201 port) -----------------
// C(MxN) = A(MxK) @ W(NxK)^T + bias.  1-D grid, nwg = (M/256)*nxt, nxt = N/256.
// MODE 0: C bf16;  MODE 1: C bf16 = gelu(val);  MODE 2: C f32 += val.
template <int MODE>
__global__ __launch_bounds__(512, 2) void k_gemm(const unsigned short* __restrict__ A,
                                                 const unsigned short* __restrict__ W,
                                                 const float* __restrict__ bias,
                                                 void* __restrict__ Cv, int K, int ldc, int nxt) {
    __shared__ __align__(16) short sL[2][2][16384];  // [buf][A|B][256 rows x 64]

    // bijective XCD swizzle
    int nwg = gridDim.x;
    int orig = blockIdx.x;
    int q8 = nwg >> 3, r8 = nwg & 7;
    int xcd = orig & 7, base = orig >> 3;
    int swz = (xcd < r8 ? xcd * (q8 + 1) : r8 * (q8 + 1) + (xcd - r8) * q8) + base;
    int tn = swz % nxt, tm = swz / nxt;

    int tid = threadIdx.x;
    int lane = tid & 63;
    int w = tid >> 6;              // 0..7
    int wm = w >> 2, wn = w & 3;   // 2 x 4 wave grid; wave tile 128x64
    int r16 = lane & 15, g = lane >> 4;

    // staging addressing: one gload16 (512 thr) covers 64 rows x 64 cols.
    // lane l -> row (w*8 + l>>3), linear chunk l&7; global src chunk inverse-
    // swizzled by XOR row&7 ( = l>>3 ).
    int rowoff = (w << 3) + (lane >> 3);                 // 0..63
    int chunkoff = ((lane & 7) ^ (lane >> 3)) << 3;      // elems
    const short* gA = (const short*)A + ((size_t)tm * 256 + rowoff) * K + chunkoff;
    const short* gB = (const short*)W + ((size_t)tn * 256 + rowoff) * K + chunkoff;
    int ldsrow = w << 9;  // w*8 rows * 64 elems

    // fragment read offsets (elems). frag row -> row*64 + ((ks*4+g)^(row&7))*8
    int ar0 = (wm * 128 + r16) * 64;
    int br0 = (wn * 64 + r16) * 64;
    int sl0 = ((0 + g) ^ (r16 & 7)) << 3;
    int sl1 = ((4 + g) ^ (r16 & 7)) << 3;

    f32x4 acc[8][4] = {};
    int NT = K >> 6;

#define STG(ls, gp, R, T) \
    gload16((gp) + (size_t)(R) * K + (size_t)(T) * 64, &sL[(T) & 1][ls][(R) * 64 + ldsrow])

    // prologue: tile0 full (8 loads); tile1 {B0..3, A0, A2} (6 loads)
    STG(0, gA, 0, 0); STG(0, gA, 64, 0); STG(0, gA, 128, 0); STG(0, gA, 192, 0);
    STG(1, gB, 0, 0); STG(1, gB, 64, 0); STG(1, gB, 128, 0); STG(1, gB, 192, 0);
    if (NT > 1) {
        STG(1, gB, 0, 1); STG(1, gB, 64, 1); STG(1, gB, 128, 1); STG(1, gB, 192, 1);
        STG(0, gA, 0, 1); STG(0, gA, 128, 1);
    }
    asm volatile("s_waitcnt vmcnt(6)" ::: "memory");
    __builtin_amdgcn_s_barrier();

    for (int t = 0; t < NT; ++t) {
        const short* bufA = &sL[t & 1][0][0];
        const short* bufB = &sL[t & 1][1][0];
        short8 bfr[4][2];

        // ---- phase 0: read all B (8) + A mfrags 0,1 (4); stage A1,A3(t+1) ----
        {
#pragma unroll
            for (int n = 0; n < 4; n++) {
                bfr[n][0] = *(const short8*)&bufB[br0 + n * 1024 + sl0];
                bfr[n][1] = *(const short8*)&bufB[br0 + n * 1024 + sl1];
            }
            short8 a00 = *(const short8*)&bufA[ar0 + sl0];
            short8 a01 = *(const short8*)&bufA[ar0 + sl1];
            short8 a10 = *(const short8*)&bufA[ar0 + 1024 + sl0];
            short8 a11 = *(const short8*)&bufA[ar0 + 1024 + sl1];
            if (t + 1 < NT) { STG(0, gA, 64, t + 1); STG(0, gA, 192, t + 1); }
            __builtin_amdgcn_s_barrier();
            asm volatile("s_waitcnt lgkmcnt(0)" ::: "memory");
            __builtin_amdgcn_sched_barrier(0);
            __builtin_amdgcn_s_setprio(1);
#pragma unroll
            for (int n = 0; n < 4; n++) {
                acc[0][n] = MFMA_(a00, bfr[n][0], acc[0][n]);
                acc[0][n] = MFMA_(a01, bfr[n][1], acc[0][n]);
                acc[1][n] = MFMA_(a10, bfr[n][0], acc[1][n]);
                acc[1][n] = MFMA_(a11, bfr[n][1], acc[1][n]);
            }
            __builtin_amdgcn_s_setprio(0);
            __builtin_amdgcn_sched_barrier(0);
            __builtin_amdgcn_s_barrier();
        }

        // ---- phases 1..3: read A mfrags (2q,2q+1); stage tile t+2 pieces ----
#define PHASEQ(MB, S1R, S1L, S2R, S2L, TAILVM)                                 \
        {                                                                      \
            short8 a00 = *(const short8*)&bufA[ar0 + (MB) * 1024 + sl0];       \
            short8 a01 = *(const short8*)&bufA[ar0 + (MB) * 1024 + sl1];       \
            short8 a10 = *(const short8*)&bufA[ar0 + (MB + 1) * 1024 + sl0];   \
            short8 a11 = *(const short8*)&bufA[ar0 + (MB + 1) * 1024 + sl1];   \
            if (t + 2 < NT) {                                                  \
                STG(S1L, (S1L ? gB : gA), S1R, t + 2);                         \
                STG(S2L, (S2L ? gB : gA), S2R, t + 2);                         \
            }                                                                  \
            __builtin_amdgcn_s_barrier();                                      \
            asm volatile("s_waitcnt lgkmcnt(0)" ::: "memory");                 \
            __builtin_amdgcn_sched_barrier(0);                                 \
            __builtin_amdgcn_s_setprio(1);                                     \
            _Pragma("unroll")                                                  \
            for (int n = 0; n < 4; n++) {                                      \
                acc[MB][n] = MFMA_(a00, bfr[n][0], acc[MB][n]);                \
                acc[MB][n] = MFMA_(a01, bfr[n][1], acc[MB][n]);                \
                acc[MB + 1][n] = MFMA_(a10, bfr[n][0], acc[MB + 1][n]);        \
                acc[MB + 1][n] = MFMA_(a11, bfr[n][1], acc[MB + 1][n]);        \
            }                                                                  \
            __builtin_amdgcn_s_setprio(0);                                     \
            __builtin_amdgcn_sched_barrier(0);                                 \
            TAILVM;                                                            \
            __builtin_amdgcn_s_barrier();                                      \
        }

        PHASEQ(2, 0, 1, 64, 1, );    // stage B0,B1(t+2)
        PHASEQ(4, 128, 1, 192, 1, ); // stage B2,B3(t+2)
        if (t + 2 < NT) {
            PHASEQ(6, 0, 0, 128, 0, asm volatile("s_waitcnt vmcnt(6)" ::: "memory"));
        } else {
            PHASEQ(6, 0, 0, 128, 0, asm volatile("s_waitcnt vmcnt(0)" ::: "memory"));
        }
#undef PHASEQ
    }
#undef STG

    // ---- epilogue ----
    size_t rbase = (size_t)tm * 256 + wm * 128 + g * 4;
    size_t cbase = (size_t)tn * 256 + wn * 64 + r16;
#pragma unroll
    for (int m = 0; m < 8; m++)
#pragma unroll
        for (int n = 0; n < 4; n++) {
            size_t col = cbase + n * 16;
            float bv = bias ? bias[col] : 0.f;
#pragma unroll
            for (int r = 0; r < 4; r++) {
                size_t row = rbase + m * 16 + r;
                float val = acc[m][n][r] + bv;
                if (MODE == 0) {
                    ((unsigned short*)Cv)[row * ldc + col] = f2bf(val);
                } else if (MODE == 1) {
                    float gv = val / (1.f + __expf(-1.702f * val));
                    ((unsigned short*)Cv)[row * ldc + col] = f2bf(gv);
                } else {
                    ((float*)Cv)[row * ldc + col] += val;
                }
            }
        }
}

// ---------------- attention: per-seq block (512 thr = 8 waves = 8 heads) ------
__global__ __launch_bounds__(512) void k_attn(const unsigned short* __restrict__ Qm,
                                              const unsigned short* __restrict__ KVm,
                                              unsigned short* __restrict__ Om) {
    __shared__ __align__(16) short sAll[3 * 17 * 520];
    __shared__ float sP[8 * 17 * 17];
    int seq = blockIdx.x;
    size_t tb = (size_t)seq * 17;
    for (int c = threadIdx.x; c < 3264; c += 512) {
        int mat = c / 1088, rem = c % 1088, row = rem >> 6, ch = rem & 63;
        const short8* src;
        if (mat == 0)
            src = (const short8*)(Qm + (tb + row) * 512 + ch * 8);
        else if (mat == 1)
            src = (const short8*)(KVm + (tb + row) * 1024 + ch * 8);
        else
            src = (const short8*)(KVm + (tb + row) * 1024 + 512 + ch * 8);
        *(short8*)&sAll[mat * (17 * 520) + row * 520 + ch * 8] = *src;
    }
    __syncthreads();
    int h = threadIdx.x >> 6, lane = threadIdx.x & 63;
    const short* sQ = sAll;
    const short* sK = sAll + 17 * 520;
    const short* sV = sAll + 2 * 17 * 520;
    int jj = lane < 17 ? lane : 0;
    for (int i = 0; i < 17; i++) {
        float acc = 0.f;
#pragma unroll
        for (int c = 0; c < 8; c++) {
            short8 q8 = *(const short8*)&sQ[i * 520 + h * 64 + c * 8];
            short8 k8 = *(const short8*)&sK[jj * 520 + h * 64 + c * 8];
#pragma unroll
            for (int e = 0; e < 8; e++) acc += bf2f(q8[e]) * bf2f(k8[e]);
        }
        float sc = (lane < 17) ? acc * 0.125f : -1e30f;
        float m = sc;
#pragma unroll
        for (int off = 32; off; off >>= 1) m = fmaxf(m, __shfl_xor(m, off));
        float p = (lane < 17) ? __expf(sc - m) : 0.f;
        float sum = p;
#pragma unroll
        for (int off = 32; off; off >>= 1) sum += __shfl_xor(sum, off);
        if (lane < 17) sP[(h * 17 + i) * 17 + lane] = p / sum;
    }
    for (int i = 0; i < 17; i++) {
        float o = 0.f;
#pragma unroll
        for (int t = 0; t < 17; t++)
            o += sP[(h * 17 + i) * 17 + t] * bf2f(sV[t * 520 + h * 64 + lane]);
        Om[(tb + i) * 512 + h * 64 + lane] = f2bf(o);
    }
}

// ---------------------------------------------------------------------------
extern "C" void kernel_launch(void* const* d_in, const int* in_sizes, int n_in,
                              void* d_out, int out_size, void* d_ws, size_t ws_size,
                              hipStream_t stream) {
    const float* image_feature = (const float*)d_in[0];
    const float* image_tokens = (const float*)d_in[1];
    const float* text_feature = (const float*)d_in[2];
    const float* text_tokens = (const float*)d_in[3];
    const int* atte_mask = (const int*)d_in[4];
    const float* img_cls = (const float*)d_in[5];
    const float* txt_cls = (const float*)d_in[6];
    const float* in_proj_w = (const float*)d_in[7];
    const float* in_proj_b = (const float*)d_in[8];
    const float* out_w = (const float*)d_in[9];
    const float* out_b = (const float*)d_in[10];
    const float* ln1_w = (const float*)d_in[11];
    const float* ln1_b = (const float*)d_in[12];
    const float* ln2_w = (const float*)d_in[13];
    const float* ln2_b = (const float*)d_in[14];
    const float* ln3_w = (const float*)d_in[15];
    const float* ln3_b = (const float*)d_in[16];
    const float* fc_w = (const float*)d_in[17];
    const float* fc_b = (const float*)d_in[18];
    const float* proj_w = (const float*)d_in[19];
    const float* proj_b = (const float*)d_in[20];

    // ---- workspace layout (adaptive; see round-2 notes) ----
    char* ws = (char*)d_ws;
    const size_t OFF_K = 12582912;
    const size_t OFF_CH = OFF_K + 35651584;  // 48,234,496
    size_t avail = ws_size > OFF_CH ? ws_size - OFF_CH : 0;
    int C = 2048;  // seqs per chunk (multiple of 256 for 256-row M-tiles)
    while (C > 256 && (size_t)87040 * C > avail) C >>= 1;
    int nch = 2048 / C;

    unsigned short* wbf = (unsigned short*)ws;
    unsigned short* w_inproj = wbf;                // 2*1536*512 elems
    unsigned short* w_outp = wbf + 1572864;        // 2*512*512
    unsigned short* w_fc = wbf + 2097152;          // 2*2048*512
    unsigned short* w_proj = wbf + 4194304;        // 2*512*2048
    unsigned short* kstream = (unsigned short*)(ws + OFF_K);
    char* chreg = ws + OFF_CH;
    // early overlay
    float* img_n = (float*)(chreg + 0);            // 12,845,056
    float* txt_n = (float*)(chreg + 12845056);     //  5,046,272
    float* isum = (float*)(chreg + 17891328);      //     65,536
    float* tmask = (float*)(chreg + 17956864);     //     65,536
    float* simg = (float*)(chreg + 18022400);      //    802,816
    float* stxt = (float*)(chreg + 18825216);      //    315,392
    int* idx_i = (int*)(chreg + 19140608);         //     65,536
    int* idx_t = (int*)(chreg + 19206144);         //     65,536
    // chunk-time pointers
    unsigned short* qn = (unsigned short*)chreg;                      // 17408*C B
    unsigned short* qkvQ = (unsigned short*)(chreg + (size_t)17408 * C);
    unsigned short* qkvKV = (unsigned short*)(chreg + (size_t)34816 * C);
    unsigned short* atto = (unsigned short*)(chreg + (size_t)69632 * C);
    unsigned short* hbuf = qkvQ;  // 69632*C B, overlays qkvQ+qkvKV+atto
    float* q = (float*)d_out;

    // weights -> bf16
    k_f2b<<<1024, 256, 0, stream>>>(in_proj_w, w_inproj, 1572864);
    k_f2b<<<1024, 256, 0, stream>>>(out_w, w_outp, 524288);
    k_f2b<<<1024, 256, 0, stream>>>(fc_w, w_fc, 2097152);
    k_f2b<<<1024, 256, 0, stream>>>(proj_w, w_proj, 2097152);

    // token normalize
    k_l2norm<<<6272, 256, 0, stream>>>(image_tokens, img_n);
    k_l2norm<<<2464, 256, 0, stream>>>(text_tokens, txt_n);

    // factored score vectors
    k_colsum<<<32, 512, 0, stream>>>(img_n, nullptr, isum, 196);
    k_colsum<<<32, 512, 0, stream>>>(txt_n, atte_mask, tmask, 77);

    // scores + top-k + gather (q -> d_out f32, k -> bf16)
    k_scores<<<1024, 256, 0, stream>>>(img_n, tmask, simg, 196, 0);
    k_scores<<<1024, 256, 0, stream>>>(txt_n, isum, stxt, 77, 1);
    k_topk<<<2048, 64, 0, stream>>>(simg, stxt, idx_i, idx_t);
    k_gather<<<69632, 128, 0, stream>>>(img_n, txt_n, image_feature, text_feature,
                                        img_cls, txt_cls, idx_i, idx_t, q, kstream);

    // 2-layer cross-attention transformer, chunked over sequences
    for (int ch = 0; ch < nch; ch++) {
        size_t r0 = (size_t)ch * C * 17;
        float* qc = q + r0 * 512;
        const unsigned short* kc = kstream + r0 * 512;
        int rowsC = 17 * C;
        int gmt = rowsC / 256;  // 256-row M-tiles (17*C % 256 == 0 for C>=256)
        for (int l = 0; l < 2; l++) {
            const unsigned short* Wq = w_inproj + (size_t)l * 786432;
            const unsigned short* Wkv = Wq + 262144;
            const float* bq = in_proj_b + l * 1536;
            const float* bkv = bq + 512;
            k_ln<0><<<rowsC, 256, 0, stream>>>(qc, ln1_w + l * 512, ln1_b + l * 512, qn);
            k_gemm<0><<<gmt * 2, 512, 0, stream>>>(qn, Wq, bq, qkvQ, 512, 512, 2);
            k_ln<1><<<rowsC, 256, 0, stream>>>(kc, ln2_w + l * 512, ln2_b + l * 512, qn);
            k_gemm<0><<<gmt * 4, 512, 0, stream>>>(qn, Wkv, bkv, qkvKV, 512, 1024, 4);
            k_attn<<<C, 512, 0, stream>>>(qkvQ, qkvKV, atto);
            k_gemm<2><<<gmt * 2, 512, 0, stream>>>(atto, w_outp + (size_t)l * 262144,
                                                   out_b + l * 512, qc, 512, 512, 2);
            k_ln<0><<<rowsC, 256, 0, stream>>>(qc, ln3_w + l * 512, ln3_b + l * 512, qn);
            k_gemm<1><<<gmt * 8, 512, 0, stream>>>(qn, w_fc + (size_t)l * 1048576,
                                                   fc_b + l * 2048, hbuf, 512, 2048, 8);
            k_gemm<2><<<gmt * 2, 512, 0, stream>>>(hbuf, w_proj + (size_t)l * 1048576,
                                                   proj_b + l * 512, qc, 2048, 512, 2);
        }
    }
}

// Round 7
// 1351.773 us; speedup vs baseline: 1.1782x; 1.1782x over previous
//
#include <hip/hip_runtime.h>
#include <hip/hip_bf16.h>
#include <stdint.h>

// ---------------------------------------------------------------------------
// Alignment_49735721287759: CLIP-style alignment head on MI355X (gfx950)
// Round 7 GEMM: 128x128 tile, BK=32 units, ring-2 LDS (32KB -> ~5 blocks/CU),
// counted vmcnt(4) (never drain mid-loop), conflict-free XOR swizzle
// s = g ^ ((row ^ row>>2) & 3) on both stage-source and read, setprio,
// bijective XCD swizzle. TLP-based latency hiding (m97/m114 mechanism).
// ---------------------------------------------------------------------------

typedef __attribute__((ext_vector_type(8))) short short8;
typedef __attribute__((ext_vector_type(4))) float f32x4;

__device__ __forceinline__ float bf2f(short u) {
    return __uint_as_float(((uint32_t)(uint16_t)u) << 16);
}
__device__ __forceinline__ unsigned short f2bf(float f) {
    __hip_bfloat16 h = __float2bfloat16(f);
    return *reinterpret_cast<unsigned short*>(&h);
}
__device__ __forceinline__ void gload16(const void* g, void* l) {
    __builtin_amdgcn_global_load_lds(
        (const __attribute__((address_space(1))) unsigned int*)g,
        (__attribute__((address_space(3))) unsigned int*)l, 16, 0, 0);
}

// ---------------- f32 -> bf16 convert (weights) ----------------
__global__ __launch_bounds__(256) void k_f2b(const float* __restrict__ in,
                                             unsigned short* __restrict__ out, int n) {
    for (int i = blockIdx.x * 256 + threadIdx.x; i < n; i += gridDim.x * 256)
        out[i] = f2bf(in[i]);
}

// ---------------- row L2 normalize (512-wide rows) ----------------
__global__ __launch_bounds__(256) void k_l2norm(const float* __restrict__ in,
                                                float* __restrict__ out) {
    size_t row = blockIdx.x;
    const float* x = in + row * 512;
    int t = threadIdx.x;
    float a0 = x[t], a1 = x[t + 256];
    float ss = a0 * a0 + a1 * a1;
#pragma unroll
    for (int off = 32; off; off >>= 1) ss += __shfl_xor(ss, off);
    __shared__ float s4[4];
    if ((t & 63) == 0) s4[t >> 6] = ss;
    __syncthreads();
    float tot = s4[0] + s4[1] + s4[2] + s4[3];
    float inv = 1.0f / sqrtf(tot);
    out[row * 512 + t] = a0 * inv;
    out[row * 512 + t + 256] = a1 * inv;
}

// ---------------- column sum over tokens (optionally masked) ----------------
__global__ __launch_bounds__(512) void k_colsum(const float* __restrict__ tok,
                                                const int* __restrict__ mask,
                                                float* __restrict__ out, int R) {
    int b = blockIdx.x;
    int d = threadIdx.x;  // 512 threads
    float acc = 0.f;
    for (int r = 0; r < R; r++) {
        float m = mask ? (float)mask[b * R + r] : 1.f;
        acc += m * tok[((size_t)b * R + r) * 512 + d];
    }
    out[b * 512 + d] = acc;
}

// ---------------- factored scores ----------------
__global__ __launch_bounds__(256) void k_scores(const float* __restrict__ tok,
                                                const float* __restrict__ vec,
                                                float* __restrict__ out, int R, int swap) {
    int bid = blockIdx.x;
    int i = bid >> 5, j = bid & 31;
    int tb = swap ? j : i;
    int vb = swap ? i : j;
    __shared__ float sv[512];
    for (int t = threadIdx.x; t < 512; t += 256) sv[t] = vec[vb * 512 + t];
    __syncthreads();
    int wv = threadIdx.x >> 6, lane = threadIdx.x & 63;
    for (int r = wv; r < R; r += 4) {
        const float* tr = tok + ((size_t)tb * R + r) * 512;
        float acc = 0.f;
#pragma unroll
        for (int c = 0; c < 8; c++) {
            int d = lane + c * 64;
            acc += tr[d] * sv[d];
        }
#pragma unroll
        for (int off = 32; off; off >>= 1) acc += __shfl_xor(acc, off);
        if (lane == 0) out[(size_t)bid * R + r] = acc;
    }
}

// ---------------- top-16 (values desc, ties -> lowest idx), output sorted asc
__global__ __launch_bounds__(64) void k_topk(const float* __restrict__ simg,
                                             const float* __restrict__ stxt,
                                             int* __restrict__ idx_i, int* __restrict__ idx_t) {
    int bid = blockIdx.x;  // 0..2047: first 1024 img (n=196), then txt (n=77)
    bool isimg = bid < 1024;
    int ij = isimg ? bid : bid - 1024;
    const float* s = isimg ? simg + (size_t)ij * 196 : stxt + (size_t)ij * 77;
    int n = isimg ? 196 : 77;
    int* out = (isimg ? idx_i : idx_t) + ij * 16;
    int lane = threadIdx.x;
    float v[4];
    int ids[4];
#pragma unroll
    for (int k = 0; k < 4; k++) {
        int id = lane + k * 64;
        ids[k] = id;
        v[k] = (id < n) ? s[id] : -3.0e38f;
    }
    __shared__ int sel[16];
    for (int r = 0; r < 16; r++) {
        float bv = v[0];
        int bi = ids[0];
#pragma unroll
        for (int k = 1; k < 4; k++)
            if (v[k] > bv) { bv = v[k]; bi = ids[k]; }
#pragma unroll
        for (int off = 32; off; off >>= 1) {
            float ov = __shfl_xor(bv, off);
            int oi = __shfl_xor(bi, off);
            if (ov > bv || (ov == bv && oi < bi)) { bv = ov; bi = oi; }
        }
        if (lane == 0) sel[r] = bi;
#pragma unroll
        for (int k = 0; k < 4; k++)
            if (ids[k] == bi) v[k] = -3.0e38f;
    }
    if (lane == 0) {
        for (int a = 1; a < 16; a++) {
            int key = sel[a];
            int b = a - 1;
            while (b >= 0 && sel[b] > key) { sel[b + 1] = sel[b]; b--; }
            sel[b + 1] = key;
        }
        for (int a = 0; a < 16; a++) out[a] = sel[a];
    }
}

// ---------------- gather q (f32, into d_out) / k (bf16) token rows ----------
__global__ __launch_bounds__(128) void k_gather(const float* __restrict__ img_n,
                                                const float* __restrict__ txt_n,
                                                const float* __restrict__ img_feat,
                                                const float* __restrict__ txt_feat,
                                                const float* __restrict__ img_cls,
                                                const float* __restrict__ txt_cls,
                                                const int* __restrict__ idx_i,
                                                const int* __restrict__ idx_t,
                                                float* __restrict__ q,
                                                unsigned short* __restrict__ k) {
    int rid = blockIdx.x;  // 0..69631
    int buf = rid / 34816;
    int rem = rid % 34816;
    int seq = rem / 17, t = rem % 17;
    int c = seq >> 10, ij = seq & 1023, i = ij >> 5, j = ij & 31;
    const float* src;
    if (buf == 0) {  // q tensor
        if (c == 0)
            src = (t == 0) ? img_cls : img_n + ((size_t)i * 196 + idx_i[ij * 16 + t - 1]) * 512;
        else
            src = (t == 0) ? txt_cls : txt_n + ((size_t)j * 77 + idx_t[ij * 16 + t - 1]) * 512;
    } else {  // k tensor
        if (c == 0)
            src = (t == 0) ? (txt_feat + (size_t)j * 512)
                           : txt_n + ((size_t)j * 77 + idx_t[ij * 16 + t - 1]) * 512;
        else
            src = (t == 0) ? (img_feat + (size_t)i * 512)
                           : img_n + ((size_t)i * 196 + idx_i[ij * 16 + t - 1]) * 512;
    }
    float4 v = ((const float4*)src)[threadIdx.x];
    size_t row = (size_t)seq * 17 + t;
    if (buf == 0) {
        ((float4*)(q + row * 512))[threadIdx.x] = v;
    } else {
        ushort4 o;
        o.x = f2bf(v.x); o.y = f2bf(v.y); o.z = f2bf(v.z); o.w = f2bf(v.w);
        ((ushort4*)(k + row * 512))[threadIdx.x] = o;
    }
}

// ---------------- LayerNorm 512-wide -> bf16 out; BF: input bf16 else f32 ----
template <int BF>
__global__ __launch_bounds__(256) void k_ln(const void* __restrict__ xv,
                                            const float* __restrict__ w,
                                            const float* __restrict__ b,
                                            unsigned short* __restrict__ out) {
    size_t row = blockIdx.x;
    int t = threadIdx.x;
    float a0, a1;
    if (BF) {
        const short* xr = (const short*)xv + row * 512;
        a0 = bf2f(xr[t]);
        a1 = bf2f(xr[t + 256]);
    } else {
        const float* xr = (const float*)xv + row * 512;
        a0 = xr[t];
        a1 = xr[t + 256];
    }
    float s = a0 + a1, qq = a0 * a0 + a1 * a1;
#pragma unroll
    for (int off = 32; off; off >>= 1) {
        s += __shfl_xor(s, off);
        qq += __shfl_xor(qq, off);
    }
    __shared__ float s4[4], q4[4];
    if ((t & 63) == 0) { s4[t >> 6] = s; q4[t >> 6] = qq; }
    __syncthreads();
    s = s4[0] + s4[1] + s4[2] + s4[3];
    qq = q4[0] + q4[1] + q4[2] + q4[3];
    float mean = s * (1.f / 512.f);
    float var = qq * (1.f / 512.f) - mean * mean;
    float rs = rsqrtf(var + 1e-5f);
    out[row * 512 + t] = f2bf((a0 - mean) * rs * w[t] + b[t]);
    out[row * 512 + t + 256] = f2bf((a1 - mean) * rs * w[t + 256] + b[t + 256]);
}

// ---------------- TLP-pipelined bf16 MFMA GEMM -------------------------------
// C(MxN) = A(MxK) @ W(NxK)^T + bias.  1-D grid, nwg = (M/128)*nxt, nxt = N/128.
// K in units of 32; LDS ring of 2 slots (16KB each: A[128][32] | B[128][32])
// = 32KB total -> ~5 blocks/CU. Per unit: wait vmcnt(4) -> barrier ->
// 8x ds_read_b128 (conflict-free swizzle) -> setprio 16 MFMA -> barrier ->
// stage unit u+2 into freed slot. Latency hidden by cross-block TLP.
// Swizzle: granule s = g ^ ((row ^ (row>>2)) & 3)  (2-way on reads = free);
// staging source chunk applies the same involution (both-sides rule).
// MODE 0: C bf16;  MODE 1: C bf16 = gelu(val);  MODE 2: C f32 += val.
template <int MODE>
__global__ __launch_bounds__(256) void k_gemm(const unsigned short* __restrict__ A,
                                              const unsigned short* __restrict__ W,
                                              const float* __restrict__ bias,
                                              void* __restrict__ Cv, int K, int ldc, int nxt) {
    __shared__ __align__(16) short sU[2][8192];  // slot: A 4096 elems | B 4096 elems

    // bijective XCD swizzle (m204 variant)
    int nwg = gridDim.x;
    int orig = blockIdx.x;
    int q8 = nwg >> 3, r8 = nwg & 7;
    int xcd = orig & 7, base = orig >> 3;
    int swz = (xcd < r8 ? xcd * (q8 + 1) : r8 * (q8 + 1) + (xcd - r8) * q8) + base;
    int tn = swz % nxt, tm = swz / nxt;

    int tid = threadIdx.x;
    int lane = tid & 63;
    int w = tid >> 6;
    int wm = w >> 1, wn = w & 1;
    int r16 = lane & 15, g = lane >> 4;

    // staging: thread t -> row t>>2 (0..63; +64 second call), granule s = t&3.
    // source chunk c = s ^ ((row ^ row>>2) & 3)  (same for row and row+64).
    int srow = tid >> 2;
    int sgran = tid & 3;
    int gchunk = (sgran ^ ((srow ^ (srow >> 2)) & 3)) * 8;  // elems
    const short* gA = (const short*)A + ((size_t)tm * 128 + srow) * K + gchunk;
    const short* gB = (const short*)W + ((size_t)tn * 128 + srow) * K + gchunk;
    int ldst = tid * 8;  // dest granule index = tid (linear per wave)

    f32x4 acc[4][4] = {};
    int NU = K >> 5;  // units of 32 (K 512/2048 -> NU 16/64)

#define STAGE_UNIT(U, S)                                              \
    do {                                                              \
        size_t ko_ = (size_t)(U) * 32;                                \
        gload16(gA + ko_, &sU[(S)][ldst]);                            \
        gload16(gA + (size_t)64 * K + ko_, &sU[(S)][2048 + ldst]);    \
        gload16(gB + ko_, &sU[(S)][4096 + ldst]);                     \
        gload16(gB + (size_t)64 * K + ko_, &sU[(S)][6144 + ldst]);    \
    } while (0)

    STAGE_UNIT(0, 0);
    STAGE_UNIT(1, 1);

    int s = 0;
    for (int u = 0; u < NU; ++u) {
        if (u + 1 < NU) asm volatile("s_waitcnt vmcnt(4)" ::: "memory");
        else            asm volatile("s_waitcnt vmcnt(0)" ::: "memory");
        __builtin_amdgcn_s_barrier();
        __builtin_amdgcn_sched_barrier(0);

        const short* SA = &sU[s][0];
        const short* SB = &sU[s][4096];
        short8 a[4], b[4];
#pragma unroll
        for (int m = 0; m < 4; m++) {
            int row = wm * 64 + m * 16 + r16;
            a[m] = *(const short8*)&SA[row * 32 + ((g ^ ((row ^ (row >> 2)) & 3)) << 3)];
        }
#pragma unroll
        for (int n = 0; n < 4; n++) {
            int row = wn * 64 + n * 16 + r16;
            b[n] = *(const short8*)&SB[row * 32 + ((g ^ ((row ^ (row >> 2)) & 3)) << 3)];
        }
        __builtin_amdgcn_s_setprio(1);
#pragma unroll
        for (int m = 0; m < 4; m++)
#pragma unroll
            for (int n = 0; n < 4; n++)
                acc[m][n] = __builtin_amdgcn_mfma_f32_16x16x32_bf16(a[m], b[n], acc[m][n], 0, 0, 0);
        __builtin_amdgcn_s_setprio(0);
        __builtin_amdgcn_sched_barrier(0);
        __builtin_amdgcn_s_barrier();
        if (u + 2 < NU) STAGE_UNIT(u + 2, s);
        s ^= 1;
    }
#undef STAGE_UNIT

    size_t rbase = (size_t)tm * 128 + wm * 64 + g * 4;
    size_t cbase = (size_t)tn * 128 + wn * 64 + r16;
#pragma unroll
    for (int m = 0; m < 4; m++)
#pragma unroll
        for (int n = 0; n < 4; n++) {
            size_t col = cbase + n * 16;
            float bv = bias ? bias[col] : 0.f;
#pragma unroll
            for (int r = 0; r < 4; r++) {
                size_t row = rbase + m * 16 + r;
                float val = acc[m][n][r] + bv;
                if (MODE == 0) {
                    ((unsigned short*)Cv)[row * ldc + col] = f2bf(val);
                } else if (MODE == 1) {
                    float gv = val / (1.f + __expf(-1.702f * val));
                    ((unsigned short*)Cv)[row * ldc + col] = f2bf(gv);
                } else {
                    ((float*)Cv)[row * ldc + col] += val;
                }
            }
        }
}

// ---------------- attention: per-seq block (512 thr = 8 waves = 8 heads) ------
__global__ __launch_bounds__(512) void k_attn(const unsigned short* __restrict__ Qm,
                                              const unsigned short* __restrict__ KVm,
                                              unsigned short* __restrict__ Om) {
    __shared__ __align__(16) short sAll[3 * 17 * 520];
    __shared__ float sP[8 * 17 * 17];
    int seq = blockIdx.x;
    size_t tb = (size_t)seq * 17;
    for (int c = threadIdx.x; c < 3264; c += 512) {
        int mat = c / 1088, rem = c % 1088, row = rem >> 6, ch = rem & 63;
        const short8* src;
        if (mat == 0)
            src = (const short8*)(Qm + (tb + row) * 512 + ch * 8);
        else if (mat == 1)
            src = (const short8*)(KVm + (tb + row) * 1024 + ch * 8);
        else
            src = (const short8*)(KVm + (tb + row) * 1024 + 512 + ch * 8);
        *(short8*)&sAll[mat * (17 * 520) + row * 520 + ch * 8] = *src;
    }
    __syncthreads();
    int h = threadIdx.x >> 6, lane = threadIdx.x & 63;
    const short* sQ = sAll;
    const short* sK = sAll + 17 * 520;
    const short* sV = sAll + 2 * 17 * 520;
    int jj = lane < 17 ? lane : 0;
    for (int i = 0; i < 17; i++) {
        float acc = 0.f;
#pragma unroll
        for (int c = 0; c < 8; c++) {
            short8 q8 = *(const short8*)&sQ[i * 520 + h * 64 + c * 8];
            short8 k8 = *(const short8*)&sK[jj * 520 + h * 64 + c * 8];
#pragma unroll
            for (int e = 0; e < 8; e++) acc += bf2f(q8[e]) * bf2f(k8[e]);
        }
        float sc = (lane < 17) ? acc * 0.125f : -1e30f;
        float m = sc;
#pragma unroll
        for (int off = 32; off; off >>= 1) m = fmaxf(m, __shfl_xor(m, off));
        float p = (lane < 17) ? __expf(sc - m) : 0.f;
        float sum = p;
#pragma unroll
        for (int off = 32; off; off >>= 1) sum += __shfl_xor(sum, off);
        if (lane < 17) sP[(h * 17 + i) * 17 + lane] = p / sum;
    }
    for (int i = 0; i < 17; i++) {
        float o = 0.f;
#pragma unroll
        for (int t = 0; t < 17; t++)
            o += sP[(h * 17 + i) * 17 + t] * bf2f(sV[t * 520 + h * 64 + lane]);
        Om[(tb + i) * 512 + h * 64 + lane] = f2bf(o);
    }
}

// ---------------------------------------------------------------------------
extern "C" void kernel_launch(void* const* d_in, const int* in_sizes, int n_in,
                              void* d_out, int out_size, void* d_ws, size_t ws_size,
                              hipStream_t stream) {
    const float* image_feature = (const float*)d_in[0];
    const float* image_tokens = (const float*)d_in[1];
    const float* text_feature = (const float*)d_in[2];
    const float* text_tokens = (const float*)d_in[3];
    const int* atte_mask = (const int*)d_in[4];
    const float* img_cls = (const float*)d_in[5];
    const float* txt_cls = (const float*)d_in[6];
    const float* in_proj_w = (const float*)d_in[7];
    const float* in_proj_b = (const float*)d_in[8];
    const float* out_w = (const float*)d_in[9];
    const float* out_b = (const float*)d_in[10];
    const float* ln1_w = (const float*)d_in[11];
    const float* ln1_b = (const float*)d_in[12];
    const float* ln2_w = (const float*)d_in[13];
    const float* ln2_b = (const float*)d_in[14];
    const float* ln3_w = (const float*)d_in[15];
    const float* ln3_b = (const float*)d_in[16];
    const float* fc_w = (const float*)d_in[17];
    const float* fc_b = (const float*)d_in[18];
    const float* proj_w = (const float*)d_in[19];
    const float* proj_b = (const float*)d_in[20];

    // ---- workspace layout (adaptive; see round-2 notes) ----
    char* ws = (char*)d_ws;
    const size_t OFF_K = 12582912;
    const size_t OFF_CH = OFF_K + 35651584;  // 48,234,496
    size_t avail = ws_size > OFF_CH ? ws_size - OFF_CH : 0;
    int C = 2048;  // seqs per chunk
    while (C > 256 && (size_t)87040 * C > avail) C >>= 1;
    int nch = 2048 / C;

    unsigned short* wbf = (unsigned short*)ws;
    unsigned short* w_inproj = wbf;                // 2*1536*512 elems
    unsigned short* w_outp = wbf + 1572864;        // 2*512*512
    unsigned short* w_fc = wbf + 2097152;          // 2*2048*512
    unsigned short* w_proj = wbf + 4194304;        // 2*512*2048
    unsigned short* kstream = (unsigned short*)(ws + OFF_K);
    char* chreg = ws + OFF_CH;
    // early overlay
    float* img_n = (float*)(chreg + 0);            // 12,845,056
    float* txt_n = (float*)(chreg + 12845056);     //  5,046,272
    float* isum = (float*)(chreg + 17891328);      //     65,536
    float* tmask = (float*)(chreg + 17956864);     //     65,536
    float* simg = (float*)(chreg + 18022400);      //    802,816
    float* stxt = (float*)(chreg + 18825216);      //    315,392
    int* idx_i = (int*)(chreg + 19140608);         //     65,536
    int* idx_t = (int*)(chreg + 19206144);         //     65,536
    // chunk-time pointers
    unsigned short* qn = (unsigned short*)chreg;                      // 17408*C B
    unsigned short* qkvQ = (unsigned short*)(chreg + (size_t)17408 * C);
    unsigned short* qkvKV = (unsigned short*)(chreg + (size_t)34816 * C);
    unsigned short* atto = (unsigned short*)(chreg + (size_t)69632 * C);
    unsigned short* hbuf = qkvQ;  // 69632*C B, overlays qkvQ+qkvKV+atto
    float* q = (float*)d_out;

    // weights -> bf16
    k_f2b<<<1024, 256, 0, stream>>>(in_proj_w, w_inproj, 1572864);
    k_f2b<<<1024, 256, 0, stream>>>(out_w, w_outp, 524288);
    k_f2b<<<1024, 256, 0, stream>>>(fc_w, w_fc, 2097152);
    k_f2b<<<1024, 256, 0, stream>>>(proj_w, w_proj, 2097152);

    // token normalize
    k_l2norm<<<6272, 256, 0, stream>>>(image_tokens, img_n);
    k_l2norm<<<2464, 256, 0, stream>>>(text_tokens, txt_n);

    // factored score vectors
    k_colsum<<<32, 512, 0, stream>>>(img_n, nullptr, isum, 196);
    k_colsum<<<32, 512, 0, stream>>>(txt_n, atte_mask, tmask, 77);

    // scores + top-k + gather (q -> d_out f32, k -> bf16)
    k_scores<<<1024, 256, 0, stream>>>(img_n, tmask, simg, 196, 0);
    k_scores<<<1024, 256, 0, stream>>>(txt_n, isum, stxt, 77, 1);
    k_topk<<<2048, 64, 0, stream>>>(simg, stxt, idx_i, idx_t);
    k_gather<<<69632, 128, 0, stream>>>(img_n, txt_n, image_feature, text_feature,
                                        img_cls, txt_cls, idx_i, idx_t, q, kstream);

    // 2-layer cross-attention transformer, chunked over sequences
    for (int ch = 0; ch < nch; ch++) {
        size_t r0 = (size_t)ch * C * 17;
        float* qc = q + r0 * 512;
        const unsigned short* kc = kstream + r0 * 512;
        int rowsC = 17 * C;
        int gmt = rowsC / 128;  // M-tiles
        for (int l = 0; l < 2; l++) {
            const unsigned short* Wq = w_inproj + (size_t)l * 786432;
            const unsigned short* Wkv = Wq + 262144;
            const float* bq = in_proj_b + l * 1536;
            const float* bkv = bq + 512;
            k_ln<0><<<rowsC, 256, 0, stream>>>(qc, ln1_w + l * 512, ln1_b + l * 512, qn);
            k_gemm<0><<<gmt * 4, 256, 0, stream>>>(qn, Wq, bq, qkvQ, 512, 512, 4);
            k_ln<1><<<rowsC, 256, 0, stream>>>(kc, ln2_w + l * 512, ln2_b + l * 512, qn);
            k_gemm<0><<<gmt * 8, 256, 0, stream>>>(qn, Wkv, bkv, qkvKV, 512, 1024, 8);
            k_attn<<<C, 512, 0, stream>>>(qkvQ, qkvKV, atto);
            k_gemm<2><<<gmt * 4, 256, 0, stream>>>(atto, w_outp + (size_t)l * 262144,
                                                   out_b + l * 512, qc, 512, 512, 4);
            k_ln<0><<<rowsC, 256, 0, stream>>>(qc, ln3_w + l * 512, ln3_b + l * 512, qn);
            k_gemm<1><<<gmt * 16, 256, 0, stream>>>(qn, w_fc + (size_t)l * 1048576,
                                                    fc_b + l * 2048, hbuf, 512, 2048, 16);
            k_gemm<2><<<gmt * 4, 256, 0, stream>>>(hbuf, w_proj + (size_t)l * 1048576,
                                                   proj_b + l * 512, qc, 2048, 512, 4);
        }
    }
}